// Round 5
// baseline (793.930 us; speedup 1.0000x reference)
//
#include <hip/hip_runtime.h>
#include <hip/hip_bf16.h>

#define IN_SIZE 256
#define N_NODES 1024
#define DEG 32
#define BATCH 16384
#define OUT_SIZE 16
#define N_ROWS (IN_SIZE + N_NODES)   // 1280 activation rows
#define CPB 16                        // batch columns per block (fp32 -> 80 KB LDS)
#define PAIRS (CPB / 2)               // 8 float2 col-pairs per row

// ---------------------------------------------------------------------------
// Runtime dtype detector (proven in rounds 2-3). bf16 -> flag=1.
// ---------------------------------------------------------------------------
__global__ __launch_bounds__(64) void ne_detect(const void* __restrict__ xraw,
                                                int* __restrict__ flag) {
    const unsigned short* xb = (const unsigned short*)xraw;
    const int tid = threadIdx.x;
    int plausible = 0;
    for (int k = tid; k < 2048; k += 64) {
        const float v = __uint_as_float((unsigned)xb[2 * k] << 16);
        const float a = fabsf(v);
        plausible += (a == 0.0f) || (a > 1e-3f && a < 1e3f) ? 1 : 0;
    }
    for (int off = 32; off > 0; off >>= 1) plausible += __shfl_down(plausible, off);
    if (tid == 0) *flag = (plausible >= (2048 * 9) / 10) ? 1 : 0;
}

// ---------------------------------------------------------------------------
// Weights -> fp32 (exact widening from bf16) so the hot loop is branch-free.
// ---------------------------------------------------------------------------
__global__ __launch_bounds__(256) void ne_prep_w(const void* __restrict__ wraw,
                                                 float* __restrict__ wf,
                                                 const int* __restrict__ flag) {
    const int isb = *flag;
    const int k = blockIdx.x * 256 + threadIdx.x;
    if (k < N_NODES * DEG) {
        if (isb) wf[k] = __uint_as_float((unsigned)((const unsigned short*)wraw)[k] << 16);
        else     wf[k] = ((const float*)wraw)[k];
    }
}

// ---------------------------------------------------------------------------
// x [BATCH][IN_SIZE] -> xT [IN_SIZE][BATCH] fp32 (exact).
// ---------------------------------------------------------------------------
__global__ __launch_bounds__(1024) void ne_transpose_x(const void* __restrict__ xraw,
                                                       float* __restrict__ xT,
                                                       const int* __restrict__ flag) {
    const int isb = *flag;
    __shared__ float tile[64][65];
    const int tx = threadIdx.x;                  // 0..63
    const int ty = threadIdx.y;                  // 0..15
    const int p0 = blockIdx.x * 64;
    const int b0 = blockIdx.y * 64;

#pragma unroll
    for (int r = 0; r < 4; ++r) {
        const int bl = ty + 16 * r;
        const size_t off = (size_t)(b0 + bl) * IN_SIZE + p0 + tx;
        tile[bl][tx] = isb ? __uint_as_float((unsigned)((const unsigned short*)xraw)[off] << 16)
                           : ((const float*)xraw)[off];
    }
    __syncthreads();
#pragma unroll
    for (int r = 0; r < 4; ++r) {
        const int p = ty + 16 * r;
        xT[(size_t)(p0 + p) * BATCH + b0 + tx] = tile[tx][p];
    }
}

// ---------------------------------------------------------------------------
// helpers
// ---------------------------------------------------------------------------
template <int CTRL>
__device__ __forceinline__ float dpp_add(float v) {        // VALU cross-lane, no DS pipe
    const int o = __builtin_amdgcn_mov_dpp(__float_as_int(v), CTRL, 0xF, 0xF, true);
    return v + __int_as_float(o);
}
__device__ __forceinline__ float tanh_fast(float a) {      // proven (round 3, 0.0039)
    const float s = __expf(-2.0f * fabsf(a));
    return copysignf((1.0f - s) * __builtin_amdgcn_rcpf(1.0f + s), a);
}

// ---------------------------------------------------------------------------
// Sequential network, fp32 activations. 1024 single-wave blocks, 16 cols each;
// 1280-row history in 80 KB static LDS (2 blocks/CU -> 2 residency rounds,
// structural: fp32 caps LDS at 32 cols/CU). Lane = (q=lane&7: d-group of 4
// gathers) x (p=lane>>3: col-pair). Per node: 4 ds_read_b64 + 1 masked
// ds_write_b64; reduction across q = pure-VALU DPP (xor1, xor2, mirror7).
// Node i-1's LDS write is deferred into iter i AND reads(i+1) are issued
// before dot(i): the single unwritten row (255+i at consume time) is patched
// in-register from the previous result. Single wave => in-order DS => no
// barriers anywhere.
// ---------------------------------------------------------------------------
__global__ __launch_bounds__(64) void ne_forward(const float* __restrict__ xT,
                                                 const float* __restrict__ wf,
                                                 const int* __restrict__ in_idxs,
                                                 void* __restrict__ outraw,
                                                 const int* __restrict__ flag) {
    __shared__ float2 act2[N_ROWS * PAIRS];      // 80 KB
    const int lane = threadIdx.x;
    const int q = lane & 7;                      // d-group
    const int p = lane >> 3;                     // col-pair 0..7
    const int c0 = blockIdx.x * CPB;
    const int isb = *flag;                       // uniform

    // ---- seed rows 0..255 from xT (float2 loads, ds_write_b64) ----
    {
        const int c2 = lane & 7, rr = lane >> 3; // 8 rows / iter
#pragma unroll 4
        for (int k = 0; k < 32; ++k) {
            const int row = k * 8 + rr;
            act2[row * PAIRS + c2] = *(const float2*)(xT + (size_t)row * BATCH + c0 + 2 * c2);
        }
    }

    float* outf = (float*)outraw;
    unsigned* outb = (unsigned*)outraw;

    const int off0 = q * 4;
    int4   id = *(const int4*)(in_idxs + off0);          // node 0
    float4 wv = *(const float4*)(wf + off0);
    float2 g0 = act2[id.x * PAIRS + p], g1 = act2[id.y * PAIRS + p];
    float2 g2 = act2[id.z * PAIRS + p], g3 = act2[id.w * PAIRS + p];

    int4   nid = *(const int4*)(in_idxs + DEG + off0);   // node 1 (prefetch)
    float4 nwv = *(const float4*)(wf + DEG + off0);

    float2 pk; pk.x = 0.0f; pk.y = 0.0f;                 // node i-1 result

    for (int i = 0; i < N_NODES; ++i) {
        // (1) deferred write of node i-1 -> row 255+i
        if (i) { if (q == 0) act2[(255 + i) * PAIRS + p] = pk; }

        // (2) issue reads(i+1) NOW (rows <= 255+i all written; row 256+i is
        //     the next iteration's patch target) -> ~1 full node of latency slack
        float2 h0, h1, h2, h3;
        if (i + 1 < N_NODES) {
            h0 = act2[nid.x * PAIRS + p]; h1 = act2[nid.y * PAIRS + p];
            h2 = act2[nid.z * PAIRS + p]; h3 = act2[nid.w * PAIRS + p];
        }

        // (3) patch + dot for node i (fp32 throughout)
        const int H = i ? (255 + i) : -1;
        float2 u0 = (id.x == H) ? pk : g0;
        float2 u1 = (id.y == H) ? pk : g1;
        float2 u2 = (id.z == H) ? pk : g2;
        float2 u3 = (id.w == H) ? pk : g3;
        float a0 = fmaf(u1.x, wv.y, u0.x * wv.x);
        float b0 = fmaf(u3.x, wv.w, u2.x * wv.z);
        float a1 = fmaf(u1.y, wv.y, u0.y * wv.x);
        float b1 = fmaf(u3.y, wv.w, u2.y * wv.z);
        float acc0 = a0 + b0;
        float acc1 = a1 + b1;

        // (4) reduce across the 8 d-groups: xor1, xor2 (quad_perm), xor4 (mirror-7)
        acc0 = dpp_add<0xB1>(acc0); acc0 = dpp_add<0x4E>(acc0); acc0 = dpp_add<0x141>(acc0);
        acc1 = dpp_add<0xB1>(acc1); acc1 = dpp_add<0x4E>(acc1); acc1 = dpp_add<0x141>(acc1);

        const float t0 = tanh_fast(acc0);
        const float t1 = tanh_fast(acc1);

        // (5) tail outputs
        if (i >= N_NODES - OUT_SIZE) {
            if (q == 0) {
                const int r = i - (N_NODES - OUT_SIZE);
                if (isb) {
                    unsigned x0 = __float_as_uint(t0); x0 = (x0 + 0x7FFFu + ((x0 >> 16) & 1u)) >> 16;
                    unsigned x1 = __float_as_uint(t1); x1 = (x1 + 0x7FFFu + ((x1 >> 16) & 1u)) >> 16;
                    outb[(size_t)r * (BATCH / 2) + (c0 >> 1) + p] = x0 | (x1 << 16);
                } else {
                    float2 v; v.x = t0; v.y = t1;
                    *(float2*)(outf + (size_t)r * BATCH + c0 + 2 * p) = v;
                }
            }
        }

        // (6) rotate; prefetch idx/w for node i+2
        pk.x = t0; pk.y = t1;
        id = nid; wv = nwv;
        g0 = h0; g1 = h1; g2 = h2; g3 = h3;
        const int nn = (i + 2 < N_NODES) ? i + 2 : N_NODES - 1;
        nid = *(const int4*)(in_idxs + (size_t)nn * DEG + off0);
        nwv = *(const float4*)(wf + (size_t)nn * DEG + off0);
    }
}

extern "C" void kernel_launch(void* const* d_in, const int* in_sizes, int n_in,
                              void* d_out, int out_size, void* d_ws, size_t ws_size,
                              hipStream_t stream) {
    const void* x   = d_in[0];                   // [BATCH][IN_SIZE]
    const void* w   = d_in[1];                   // [N_NODES][DEG]
    const int* idxs = (const int*)d_in[2];       // [N_NODES][DEG]

    float* xT = (float*)d_ws;                                        // 16 MB
    float* wf = (float*)((char*)d_ws + (size_t)IN_SIZE * BATCH * 4); // 128 KB
    int* flag = (int*)((char*)d_ws + ((ws_size - 16) & ~(size_t)15));

    ne_detect<<<1, 64, 0, stream>>>(x, flag);
    ne_prep_w<<<(N_NODES * DEG + 255) / 256, 256, 0, stream>>>(w, wf, flag);
    ne_transpose_x<<<dim3(IN_SIZE / 64, BATCH / 64), dim3(64, 16), 0, stream>>>(x, xT, flag);

    // 1024 single-wave blocks, 80 KB LDS each -> 2 blocks/CU, 2 residency rounds
    ne_forward<<<dim3(BATCH / CPB), dim3(64), 0, stream>>>(xT, wf, idxs, d_out, flag);
}

// Round 6
// 765.139 us; speedup vs baseline: 1.0376x; 1.0376x over previous
//
#include <hip/hip_runtime.h>
#include <hip/hip_bf16.h>

#define IN_SIZE 256
#define N_NODES 1024
#define DEG 32
#define BATCH 16384
#define OUT_SIZE 16
#define N_ROWS (IN_SIZE + N_NODES)   // 1280 activation rows
#define CPB 4                         // batch columns per block -> 20 KB LDS, 8 blocks/CU

// ---------------------------------------------------------------------------
// Runtime dtype detector (proven rounds 2-5). bf16 -> flag=1.
// ---------------------------------------------------------------------------
__global__ __launch_bounds__(64) void ne_detect(const void* __restrict__ xraw,
                                                int* __restrict__ flag) {
    const unsigned short* xb = (const unsigned short*)xraw;
    const int tid = threadIdx.x;
    int plausible = 0;
    for (int k = tid; k < 2048; k += 64) {
        const float v = __uint_as_float((unsigned)xb[2 * k] << 16);
        const float a = fabsf(v);
        plausible += (a == 0.0f) || (a > 1e-3f && a < 1e3f) ? 1 : 0;
    }
    for (int off = 32; off > 0; off >>= 1) plausible += __shfl_down(plausible, off);
    if (tid == 0) *flag = (plausible >= (2048 * 9) / 10) ? 1 : 0;
}

// ---------------------------------------------------------------------------
// Weights -> fp32 (exact widening from bf16) so the hot loop is branch-free.
// ---------------------------------------------------------------------------
__global__ __launch_bounds__(256) void ne_prep_w(const void* __restrict__ wraw,
                                                 float* __restrict__ wf,
                                                 const int* __restrict__ flag) {
    const int isb = *flag;
    const int k = blockIdx.x * 256 + threadIdx.x;
    if (k < N_NODES * DEG) {
        if (isb) wf[k] = __uint_as_float((unsigned)((const unsigned short*)wraw)[k] << 16);
        else     wf[k] = ((const float*)wraw)[k];
    }
}

// ---------------------------------------------------------------------------
// x [BATCH][IN_SIZE] -> xT [IN_SIZE][BATCH] fp32 (exact). Proven rounds 4-5.
// ---------------------------------------------------------------------------
__global__ __launch_bounds__(1024) void ne_transpose_x(const void* __restrict__ xraw,
                                                       float* __restrict__ xT,
                                                       const int* __restrict__ flag) {
    const int isb = *flag;
    __shared__ float tile[64][65];
    const int tx = threadIdx.x;                  // 0..63
    const int ty = threadIdx.y;                  // 0..15
    const int p0 = blockIdx.x * 64;
    const int b0 = blockIdx.y * 64;

#pragma unroll
    for (int r = 0; r < 4; ++r) {
        const int bl = ty + 16 * r;
        const size_t off = (size_t)(b0 + bl) * IN_SIZE + p0 + tx;
        tile[bl][tx] = isb ? __uint_as_float((unsigned)((const unsigned short*)xraw)[off] << 16)
                           : ((const float*)xraw)[off];
    }
    __syncthreads();
#pragma unroll
    for (int r = 0; r < 4; ++r) {
        const int p = ty + 16 * r;
        xT[(size_t)(p0 + p) * BATCH + b0 + tx] = tile[tx][p];
    }
}

// ---------------------------------------------------------------------------
// helpers
// ---------------------------------------------------------------------------
template <int CTRL>
__device__ __forceinline__ float dpp_add(float v) {        // VALU cross-lane, no DS pipe
    const int o = __builtin_amdgcn_mov_dpp(__float_as_int(v), CTRL, 0xF, 0xF, true);
    return v + __int_as_float(o);
}
__device__ __forceinline__ float tanh_fast(float a) {      // proven (rounds 3/5, 0.0039)
    const float s = __expf(-2.0f * fabsf(a));
    return copysignf((1.0f - s) * __builtin_amdgcn_rcpf(1.0f + s), a);
}

// ---------------------------------------------------------------------------
// Sequential network, fp32 activations. 4096 single-wave blocks, 4 cols each;
// 1280-row history in 20 KB static LDS -> 8 blocks/CU (LDS = exactly 160 KB)
// = 2 waves/SIMD: two independent serial chains interleave per SIMD (the
// round-5 lesson: cols/CU is LDS-capped at 32, so maximize waves, not
// cols/wave). Lane = (q=lane&15: d-group of 2 gathers) x (c=lane>>4: col).
// Per node: 2 ds_read_b32 + 1 masked ds_write_b32. Reduction across q = 4
// pure-VALU DPP stages within 16-lane rows: xor1(0xB1), xor2(0x4E),
// xor4(0x141 half-mirror), xor8(0x128 row_ror:8 == xor8). Deferred write +
// hoisted reads + single-row register patch as proven in round 5. Single
// wave => in-order DS => zero barriers.
// ---------------------------------------------------------------------------
__global__ __launch_bounds__(64) void ne_forward(const float* __restrict__ xT,
                                                 const float* __restrict__ wf,
                                                 const int* __restrict__ in_idxs,
                                                 void* __restrict__ outraw,
                                                 const int* __restrict__ flag) {
    __shared__ float act[N_ROWS * CPB];          // 20 KB
    const int lane = threadIdx.x;
    const int q = lane & 15;                     // d-group 0..15 (2 inputs each)
    const int c = lane >> 4;                     // column 0..3 (= DPP row)
    const int c0 = blockIdx.x * CPB;
    const int isb = *flag;                       // uniform

    // ---- seed rows 0..255 from xT: 16 rows x 4 cols per iter, 16B segments ----
    {
        const int sr = lane >> 2, sc = lane & 3;
#pragma unroll 4
        for (int k = 0; k < 16; ++k) {
            const int row = k * 16 + sr;
            act[row * CPB + sc] = xT[(size_t)row * BATCH + c0 + sc];
        }
    }

    float* outf = (float*)outraw;
    unsigned short* outb = (unsigned short*)outraw;

    const int off0 = q * 2;
    int2   id = *(const int2*)(in_idxs + off0);          // node 0
    float2 wv = *(const float2*)(wf + off0);
    float g0 = act[id.x * CPB + c];
    float g1 = act[id.y * CPB + c];

    int2   nid = *(const int2*)(in_idxs + DEG + off0);   // node 1 (prefetch)
    float2 nwv = *(const float2*)(wf + DEG + off0);

    float pk = 0.0f;                                     // node i-1 result (col c)

    for (int i = 0; i < N_NODES; ++i) {
        // (1) deferred write of node i-1 -> row 255+i (4 lanes, 4 consecutive dwords)
        if (i) { if (q == 0) act[(255 + i) * CPB + c] = pk; }

        // (2) issue reads(i+1) now: rows <= 255+i are valid; the single
        //     not-yet-written row (256+i) is patched at consume time.
        const float h0 = act[nid.x * CPB + c];
        const float h1 = act[nid.y * CPB + c];

        // (3) patch + dot for node i (2 products/lane, fp32)
        const int H = i ? (255 + i) : -1;
        const float u0 = (id.x == H) ? pk : g0;
        const float u1 = (id.y == H) ? pk : g1;
        float acc = fmaf(u1, wv.y, u0 * wv.x);

        // (4) reduce across 16 d-groups: 4 DPP butterflies (all within 16-lane row)
        acc = dpp_add<0xB1>(acc);                // xor1
        acc = dpp_add<0x4E>(acc);                // xor2
        acc = dpp_add<0x141>(acc);               // xor4 (row_half_mirror)
        acc = dpp_add<0x128>(acc);               // xor8 (row_ror:8)

        const float t = tanh_fast(acc);

        // (5) tail outputs (last 16 nodes)
        if (i >= N_NODES - OUT_SIZE) {
            if (q == 0) {
                const int r = i - (N_NODES - OUT_SIZE);
                if (isb) {
                    unsigned u = __float_as_uint(t);
                    u = (u + 0x7FFFu + ((u >> 16) & 1u)) >> 16;      // RNE to bf16
                    outb[(size_t)r * BATCH + c0 + c] = (unsigned short)u;
                } else {
                    outf[(size_t)r * BATCH + c0 + c] = t;
                }
            }
        }

        // (6) rotate; prefetch idx/w for node i+2
        pk = t;
        id = nid; wv = nwv;
        g0 = h0; g1 = h1;
        const int nn = (i + 2 < N_NODES) ? i + 2 : N_NODES - 1;
        nid = *(const int2*)(in_idxs + (size_t)nn * DEG + off0);
        nwv = *(const float2*)(wf + (size_t)nn * DEG + off0);
    }
}

extern "C" void kernel_launch(void* const* d_in, const int* in_sizes, int n_in,
                              void* d_out, int out_size, void* d_ws, size_t ws_size,
                              hipStream_t stream) {
    const void* x   = d_in[0];                   // [BATCH][IN_SIZE]
    const void* w   = d_in[1];                   // [N_NODES][DEG]
    const int* idxs = (const int*)d_in[2];       // [N_NODES][DEG]

    float* xT = (float*)d_ws;                                        // 16 MB
    float* wf = (float*)((char*)d_ws + (size_t)IN_SIZE * BATCH * 4); // 128 KB
    int* flag = (int*)((char*)d_ws + ((ws_size - 16) & ~(size_t)15));

    ne_detect<<<1, 64, 0, stream>>>(x, flag);
    ne_prep_w<<<(N_NODES * DEG + 255) / 256, 256, 0, stream>>>(w, wf, flag);
    ne_transpose_x<<<dim3(IN_SIZE / 64, BATCH / 64), dim3(64, 16), 0, stream>>>(x, xT, flag);

    // 4096 single-wave blocks, 20 KB LDS each -> 8 blocks/CU (2 waves/SIMD)
    ne_forward<<<dim3(BATCH / CPB), dim3(64), 0, stream>>>(xT, wf, idxs, d_out, flag);
}